// Round 3
// baseline (671.995 us; speedup 1.0000x reference)
//
#include <hip/hip_runtime.h>
#include <hip/hip_bf16.h>

#define NALGOS 64
#define NTASKS 256
#define TSTEPS 4096
#define CHUNK  256                 // steps per expand block
#define NCHUNK (TSTEPS / CHUNK)    // 16
#define SUB    64                  // steps per expand LDS sub-tile (revert to v2 best)
#define TP     257                 // expand tile pitch (t-major), odd -> conflict-free
#define LOG2E  1.44269504f

// ---------------- Phase 1: driver --------------------------------------------
// One wave per algorithm. v4: ZERO LDS reads in the steady-state loop.
// Constants repacked so entry i = {X_i, Y_{i+1}, Z_{i+2}, E_{i+2}} — step k
// needs only entry k. Each 64-step group is distributed across lanes (lane l
// holds entry grp*64+l); per step the values are extracted with v_readlane at
// a compile-time lane index. Group constants are prefetched one full group
// ahead (1 ds_read_b128 + 1 ds_read_b32 per 64 steps). The only per-step
// memory op is the 8-deep-pipelined tm row global load.
__global__ __launch_bounds__(64) void driver_kernel(
    const int* __restrict__ lx, const float* __restrict__ tmat,
    const float* __restrict__ diff, const float* __restrict__ eff_v,
    const float* __restrict__ mem_v, const float* __restrict__ boost_v,
    float* __restrict__ g_arr, float* __restrict__ ckpt) {
  __shared__ int    lx_s[TSTEPS + 16];
  __shared__ float  c_s[NTASKS];
  __shared__ float4 ptab[TSTEPS + 64];  // {X_i, Y_{i+1}, Z_{i+2}, E_{i+2}}
  __shared__ int    itab[TSTEPS + 64];  // lx[i+3] | lx[i+8]<<16

  const int a = blockIdx.x;
  const int l = threadIdx.x;
  const float eff   = eff_v[a];
  const float mem   = mem_v[a];
  const float boost = boost_v[a];
  const float e0 = eff - boost;
  const float b2 = 2.0f * boost;
  const float m2 = mem * mem;

  // stage lx into LDS (coalesced)
#pragma unroll 8
  for (int k = 0; k < TSTEPS / 64; ++k) lx_s[k * 64 + l] = lx[k * 64 + l];
  if (l < 16) lx_s[TSTEPS + l] = 0;
  // c_s[n] = -log2e / diff[n]
#pragma unroll
  for (int k = 0; k < NTASKS / 64; ++k) {
    float dk = diff[k * 64 + l];
    c_s[k * 64 + l] = -LOG2E / dk;
  }
  __syncthreads();

  // build repacked tables
  //   X_j = b2*c_s[lx[j+1]]*tmat[lx[j],lx[j+1]]
  //   Y_j = b2*c_s[lx[j+1]]*mem*tmat[lx[j-1],lx[j+1]]
  //   Z_j = e0*c_s[lx[j+1]]*(tmat[lx[j],lx[j+1]] + mem*tmat[lx[j-1],lx[j+1]])
  //   E_j = c_s[lx[j+1]]*m2
  // entry i stores {X_i, Y_{i+1}, Z_{i+2}, E_{i+2}}
#pragma unroll 2
  for (int k = 0; k < TSTEPS / 64; ++k) {
    int i  = k * 64 + l;
    int t0 = lx_s[i];
    int t1 = lx_s[i + 1];
    int t2 = lx_s[i + 2];
    int t3 = lx_s[i + 3];
    float q_i   = tmat[t0 * NTASKS + t1];   // tmat[lx[i],   lx[i+1]]
    float q2_i1 = tmat[t0 * NTASKS + t2];   // tmat[lx[i],   lx[i+2]]
    float q_i2  = tmat[t2 * NTASKS + t3];   // tmat[lx[i+2], lx[i+3]]
    float q2_i2 = tmat[t1 * NTASKS + t3];   // tmat[lx[i+1], lx[i+3]]
    float cp1 = c_s[t1];
    float cp2 = c_s[t2];
    float cp3 = c_s[t3];
    float4 e;
    e.x = b2 * cp1 * q_i;                   // X_i
    e.y = b2 * cp2 * mem * q2_i1;           // Y_{i+1}
    e.z = e0 * cp3 * (q_i2 + mem * q2_i2);  // Z_{i+2}
    e.w = cp3 * m2;                         // E_{i+2}
    ptab[i] = e;
    itab[i] = t3 | (lx_s[i + 8] << 16);
  }
  ptab[TSTEPS + l] = make_float4(0.f, 0.f, 0.f, 0.f);
  itab[TSTEPS + l] = 0;
  __syncthreads();

  const float4* rows = (const float4*)tmat;  // row r: rows[r*64 + l] (4 cols/lane)
  float* gout = g_arr + (size_t)a * TSTEPS;
  float* ck   = ckpt  + (size_t)a * NCHUNK * NTASKS;

  float r0 = 0.f, r1 = 0.f, r2 = 0.f, r3 = 0.f;
  float u = 2.0f;                 // 1 + exp2(0): W[0] = 0.5
  float keep_g = 0.f;

  // A_0 = Z_0 (q2_0 = 0), base_1 = Z_1 — computed directly (wave-uniform)
  {
    int l0 = lx_s[0], l1 = lx_s[1], l2 = lx_s[2];
    float A0 = e0 * c_s[l1] * tmat[l0 * NTASKS + l1];
    float B1 = e0 * c_s[l2] *
               (tmat[l1 * NTASKS + l2] + mem * tmat[l0 * NTASKS + l2]);
    r0 = r0; // keep order
    // assigned below after pipelines init
    (void)A0; (void)B1;
  }
  int l0 = lx_s[0], l1 = lx_s[1], l2 = lx_s[2];
  float A    = e0 * c_s[l1] * tmat[l0 * NTASKS + l1];
  float base = e0 * c_s[l2] *
               (tmat[l1 * NTASKS + l2] + mem * tmat[l0 * NTASKS + l2]);

  // lane-distributed constants: lane l holds entry grp*64+l
  float4 pc = ptab[l];
  int    ic = itab[l];
  // tm row pipeline, 8-deep (slot = k&7)
  float4 tmr[8];
#pragma unroll
  for (int k = 0; k < 8; ++k) tmr[k] = rows[lx_s[k] * 64 + l];

  for (int grp = 0; grp < TSTEPS / 64; ++grp) {
    // prefetch next group's lane-distributed constants (~64 steps of slack)
    const float4 pn  = ptab[grp * 64 + 64 + l];
    const int    in_ = itab[grp * 64 + 64 + l];
#pragma unroll
    for (int kk = 0; kk < 64; ++kk) {
      const float X = __uint_as_float(
          __builtin_amdgcn_readlane(__float_as_uint(pc.x), kk));
      const float Y = __uint_as_float(
          __builtin_amdgcn_readlane(__float_as_uint(pc.y), kk));
      const float Z = __uint_as_float(
          __builtin_amdgcn_readlane(__float_as_uint(pc.z), kk));
      const float E = __uint_as_float(
          __builtin_amdgcn_readlane(__float_as_uint(pc.w), kk));
      const int  it = __builtin_amdgcn_readlane(ic, kk);
      const float4 tm = tmr[kk & 7];

      // ---- critical chain: rcp -> fma -> exp2 -> add ----
      float w   = __builtin_amdgcn_rcpf(u);      // W[k]
      float arg = fmaf(X, w, A);
      float ev  = __builtin_amdgcn_exp2f(arg);
      u = 1.0f + ev;

      // ---- off-chain ----
      float gt = fmaf(b2, w, e0);                // g_k
      A = fmaf(Y, w, base);                      // A_{k+1}

      keep_g = (kk == l) ? gt : keep_g;

      r0 = fmaf(r0, mem, tm.x * gt);
      r1 = fmaf(r1, mem, tm.y * gt);
      r2 = fmaf(r2, mem, tm.z * gt);
      r3 = fmaf(r3, mem, tm.w * gt);

      // select res_k[lx[k+3]] -> base_{k+2} (2 steps of slack downstream)
      const int j    = it & 0xff;            // lx[k+3]
      const int lane = j >> 2;
      float h01  = (j & 1) ? r1 : r0;
      float h23  = (j & 1) ? r3 : r2;
      float hsel = (j & 2) ? h23 : h01;
      float bro = __uint_as_float(
          __builtin_amdgcn_readlane(__float_as_uint(hsel), lane));
      base = fmaf(E, bro, Z);                // base_{k+2}

      // refill tm pipeline (consumed 8 steps from now)
      const int nrow = (it >> 16) & 0xff;    // lx[k+8] — SGPR -> saddr load
      tmr[kk & 7] = rows[nrow * 64 + l];
    }
    pc = pn; ic = in_;
    // unconditional group-boundary stores
    gout[grp * 64 + l] = keep_g;
    if ((grp & 3) == 3 && grp != 63) {
      float4 s; s.x = r0; s.y = r1; s.z = r2; s.w = r3;
      ((float4*)(ck + ((grp + 1) >> 2) * NTASKS))[l] = s;
    }
  }
}

// ---------------- Phase 2: expand --------------------------------------------
// Reverted to the v2 best config: SUB=64 (256-B store runs per row), 1D grid
// with XCD-grouping swizzle — all 16 chunks of one algorithm land on the same
// XCD (blockIdx % 8 == a % 8) so partial 128-B boundary lines merge in one L2.
__global__ __launch_bounds__(256) void expand_kernel(
    const int* __restrict__ lx, const float* __restrict__ tmat,
    const float* __restrict__ diff, const float* __restrict__ mem_v,
    const float* __restrict__ g_arr, const float* __restrict__ ckpt,
    float* __restrict__ out) {
  __shared__ float tile[SUB * TP];    // t-major: tile[ts*TP + n]
  __shared__ int   lx_c[CHUNK];
  __shared__ float g_c[CHUNK];

  const int id = blockIdx.x;          // 0..1023
  const int c  = (id >> 3) & 15;      // chunk 0..15
  const int a  = (id & 7) + 8 * (id >> 7);  // algorithm 0..63 (a%8 == id%8)
  const int n  = threadIdx.x;         // column 0..255

  const float mem = mem_v[a];
  const float cn  = -LOG2E / diff[n];
  float res = (c == 0) ? 0.f : ckpt[((size_t)a * NCHUNK + c) * NTASKS + n];

  const int t0 = c * CHUNK;
  lx_c[n] = lx[t0 + n];
  g_c[n]  = g_arr[(size_t)a * TSTEPS + t0 + n];
  __syncthreads();

  if (c == 0) out[((size_t)a * NTASKS + n) * (TSTEPS + 1)] = 0.f;

  const int tq   = threadIdx.x & 15;   // t-quad within 64-wide run
  const int rloc = threadIdx.x >> 4;   // 0..15

  for (int tb = 0; tb < CHUNK; tb += SUB) {
    // compute SUB steps for own column
#pragma unroll 8
    for (int ts = 0; ts < SUB; ++ts) {
      int   task = lx_c[tb + ts];
      float g    = g_c[tb + ts];
      float tm   = tmat[task * NTASKS + n];
      res = fmaf(res, mem, tm * g);
      float w = __builtin_amdgcn_rcpf(
          1.0f + __builtin_amdgcn_exp2f(cn * res));
      tile[ts * TP + n] = fmaf(2.0f, w, -1.0f);   // sig
    }
    __syncthreads();
    // flush: 16 rows per iteration, float4 along t
    for (int rr = 0; rr < NTASKS; rr += 16) {
      const int row = rr + rloc;
      float v0 = tile[(4 * tq + 0) * TP + row];
      float v1 = tile[(4 * tq + 1) * TP + row];
      float v2 = tile[(4 * tq + 2) * TP + row];
      float v3 = tile[(4 * tq + 3) * TP + row];
      float4 v = make_float4(v0, v1, v2, v3);
      float* dst = &out[((size_t)a * NTASKS + row) * (TSTEPS + 1) +
                        t0 + tb + 4 * tq + 1];
      __builtin_memcpy(dst, &v, 16);   // dword-aligned wide store
    }
    __syncthreads();
  }
}

extern "C" void kernel_launch(void* const* d_in, const int* in_sizes, int n_in,
                              void* d_out, int out_size, void* d_ws, size_t ws_size,
                              hipStream_t stream) {
  const int*   lx    = (const int*)d_in[0];
  const float* tmat  = (const float*)d_in[1];
  const float* diff  = (const float*)d_in[2];
  const float* eff   = (const float*)d_in[3];
  const float* mem   = (const float*)d_in[4];
  const float* boost = (const float*)d_in[5];
  float* out = (float*)d_out;

  float* g_arr = (float*)d_ws;                      // 64*4096 f32 = 1 MB
  float* ckpt  = g_arr + (size_t)NALGOS * TSTEPS;   // 64*16*256 f32 = 1 MB

  driver_kernel<<<NALGOS, 64, 0, stream>>>(lx, tmat, diff, eff, mem, boost,
                                           g_arr, ckpt);
  expand_kernel<<<dim3(NCHUNK * NALGOS), 256, 0, stream>>>(
      lx, tmat, diff, mem, g_arr, ckpt, out);
}